// Round 7
// baseline (331.024 us; speedup 1.0000x reference)
//
#include <hip/hip_runtime.h>

#define B_    64
#define N_    100
#define D_    32
#define F0    96
#define F1    160
#define F2    192
#define HID   256
#define FOUT  32

typedef unsigned short u16;
typedef unsigned int   u32;
typedef u16   u16x8 __attribute__((ext_vector_type(8)));
typedef __bf16 bf16x8 __attribute__((ext_vector_type(8)));
typedef __bf16 bf16x2 __attribute__((ext_vector_type(2)));
typedef float  fx4   __attribute__((ext_vector_type(4)));

__device__ __forceinline__ u16 f2bfu(float f) {
    u32 u = __float_as_uint(f);
    u += 0x7fffu + ((u >> 16) & 1u);   // RNE
    return (u16)(u >> 16);
}
#if __has_builtin(__builtin_amdgcn_cvt_pk_bf16_f32)
__device__ __forceinline__ u32 pk2(float a, float b) {
    bf16x2 t = __builtin_amdgcn_cvt_pk_bf16_f32(a, b);
    return __builtin_bit_cast(u32, t);
}
#else
__device__ __forceinline__ u32 pk2(float a, float b) {
    return (u32)f2bfu(a) | ((u32)f2bfu(b) << 16);
}
#endif
__device__ __forceinline__ float lrelu(float v) { return fmaxf(v, 0.2f * v); }

__device__ __forceinline__ bf16x8 fragLds(const u16* p) {
    return __builtin_bit_cast(bf16x8, *(const u16x8*)p);
}
__device__ __forceinline__ bf16x8 fragGbl(const u16* __restrict__ p) {
    return __builtin_bit_cast(bf16x8, *(const u16x8*)p);
}
#define MFMA(a, b, c) __builtin_amdgcn_mfma_f32_16x16x32_bf16((a), (b), (c), 0, 0, 0)

// ---- ws layout (bytes) ----
#define OFF_P     0u
#define OFF_V     2457600u     // 6400*96*4
#define OFF_AGG   4915200u     // + 6400*96*4
#define OFF_PACK  7372800u     // + 6400*192*2
// packed weights (u16 element offsets); B-frag pack layout (verified R3)
#define PK_W1     0            // 96x160  -> 15360
#define PK_W2     15360        // 160x192 -> 30720
#define PK_N0     46080        // 224x256 -> 57344
#define PK_N1     103424       // 256x256 -> 65536
#define PK_N2     168960       // 256x32  -> 8192
#define PK_TOTAL  177152

#define PV_BLOCKS 2400         // 6400*192 / 512
#define PACK_BLOCKS 346        // 177152 / 512
#define NODE_ROWS 8
#define NODE_BLOCKS 800        // 6400 / 8

// ============================ prep ============================
__global__ __launch_bounds__(512) void prep_kernel(
    const float* __restrict__ x,
    const float* __restrict__ few0, const float* __restrict__ feb0,
    const float* __restrict__ few1, const float* __restrict__ few2,
    const float* __restrict__ fnw0, const float* __restrict__ fnw1,
    const float* __restrict__ fnw2,
    float* __restrict__ P, float* __restrict__ V, u16* __restrict__ wpack)
{
    const int blk = blockIdx.x, tid = threadIdx.x;
    if (blk < PV_BLOCKS) {
        int o = blk * 512 + tid;           // < 6400*192
        int r = o / 192, h = o - r * 192;
        const float* xr = x + r * D_;
        if (h < F0) {
            float acc = feb0[h];
            #pragma unroll
            for (int d = 0; d < D_; ++d) acc = fmaf(xr[d], few0[d * F0 + h], acc);
            P[r * F0 + h] = acc;
        } else {
            int k = h - F0;
            float acc = 0.f;
            #pragma unroll
            for (int d = 0; d < D_; ++d) acc = fmaf(xr[d], few0[(D_ + d) * F0 + k], acc);
            V[r * F0 + k] = acc;
        }
    } else {
        int p = (blk - PV_BLOCKS) * 512 + tid;   // < 177152
        const float* src; int start, Ncols, NT;
        if (p < PK_W2)      { start = PK_W1; src = few1; Ncols = F1;   NT = 10; }
        else if (p < PK_N0) { start = PK_W2; src = few2; Ncols = F2;   NT = 12; }
        else if (p < PK_N1) { start = PK_N0; src = fnw0; Ncols = HID;  NT = 16; }
        else if (p < PK_N2) { start = PK_N1; src = fnw1; Ncols = HID;  NT = 16; }
        else                { start = PK_N2; src = fnw2; Ncols = FOUT; NT = 2;  }
        int local = p - start;
        int j = local & 7, lane = (local >> 3) & 63, rest = local >> 9;
        int nt = rest % NT, kt = rest / NT;
        int n = 16 * nt + (lane & 15);
        int k = 32 * kt + 8 * (lane >> 4) + j;
        wpack[p] = f2bfu(src[k * Ncols + n]);
    }
}

// ============================ edge ============================
// one block per (b,i). Non-transposed (R3-verified): A=activations, B=weights.
// A0 fragments built IN REGISTERS (no sB0 -> 37.8 KB LDS -> 4 blocks/CU).
// All register arrays indexed only by fully-unrolled compile-time loops.
__global__ __launch_bounds__(512, 8) void edge_kernel(
    const float* __restrict__ P, const float* __restrict__ V,
    const u16* __restrict__ W1p, const u16* __restrict__ W2p,
    const float* __restrict__ feb1, const float* __restrict__ feb2,
    u16* __restrict__ agg)
{
    const int i = blockIdx.x, b = blockIdx.y;
    const int tid = threadIdx.x, ld = tid & 63, wv = tid >> 6;
    const int c = ld & 15, Q = ld >> 4;
    const int row = b * N_ + i;

    __shared__ __align__(16) u16  sA1p[7 * 5 * 64 * 8];  // 35840 B: A1 A-pack
    __shared__ __align__(16) float sP[F0];               //   384 B
    __shared__ __align__(16) float sAggP[2 * F2];        //  1536 B
    // total 37760 B -> 4 blocks/CU

    if (tid < 24) ((float4*)sP)[tid] = ((const float4*)(P + (size_t)row * F0))[tid];
    __syncthreads();

    const int wn = wv & 3, wm = wv >> 2;

    // ---- layer 1: in-register A0 A-frags + MFMA; scattered b16 epilogue ----
    {
        const int nCnt = (wn < 2) ? 3 : 2;   // f-tiles nt = wn + 4t, 10 total
        const float* Vb = V + (size_t)b * (N_ * F0);
        float bias[3];
        #pragma unroll
        for (int t = 0; t < 3; ++t) if (t < nCnt) bias[t] = feb1[16 * (wn + 4 * t) + c];

        #pragma unroll
        for (int mi = 0; mi < 4; ++mi) {
            const int mt = 4 * wm + mi;      // wm=0: 0..3 ; wm=1: 4..7(skip 7)
            if (mt < 7) {
                // A-frag: row m = 16mt + c (lane&15), k = 32kt + 8Q + j
                const int m = 16 * mt + c;
                const int mc = (m < N_) ? m : (N_ - 1);   // clamp; masked at agg
                const float* vp = Vb + mc * F0;
                bf16x8 a[3];
                #pragma unroll
                for (int kt = 0; kt < 3; ++kt) {
                    const int kb = 32 * kt + 8 * Q;
                    float4 va = *(const float4*)(vp + kb);
                    float4 vb2 = *(const float4*)(vp + kb + 4);
                    float4 pa = *(const float4*)&sP[kb];
                    float4 pb = *(const float4*)&sP[kb + 4];
                    uint4 w;
                    w.x = pk2(lrelu(pa.x + va.x), lrelu(pa.y + va.y));
                    w.y = pk2(lrelu(pa.z + va.z), lrelu(pa.w + va.w));
                    w.z = pk2(lrelu(pb.x + vb2.x), lrelu(pb.y + vb2.y));
                    w.w = pk2(lrelu(pb.z + vb2.z), lrelu(pb.w + vb2.w));
                    a[kt] = __builtin_bit_cast(bf16x8, w);
                }
                #pragma unroll
                for (int t = 0; t < 3; ++t) if (t < nCnt) {
                    const int nt = wn + 4 * t;
                    fx4 acc = (fx4){bias[t], bias[t], bias[t], bias[t]};   // D cols = f
                    #pragma unroll
                    for (int kt = 0; kt < 3; ++kt) {
                        bf16x8 bw = fragGbl(W1p + (size_t)((kt * 10 + nt) * 64 + ld) * 8);
                        acc = MFMA(a[kt], bw, acc);
                    }
                    // D rows m = 16mt + 4Q + r, col f = 16nt + c -> A-pack store
                    const int f = 16 * nt + c;
                    const int kt2 = f >> 5, lq = (f >> 3) & 3, j2 = f & 7;
                    #pragma unroll
                    for (int r = 0; r < 4; ++r)
                        sA1p[((mt * 5 + kt2) * 64 + (4 * Q + r) + 16 * lq) * 8 + j2] =
                            f2bfu(lrelu(acc[r]));
                }
            }
        }
    }
    __syncthreads();

    // ---- layer 2 + fused aggregation over m (R3-verified) ----
    {
        float aggp[3] = {0.f, 0.f, 0.f};
        float bias2[3];
        #pragma unroll
        for (int t = 0; t < 3; ++t) bias2[t] = feb2[16 * (wn + 4 * t) + c];

        #pragma unroll
        for (int mi = 0; mi < 4; ++mi) {
            const int mt = 4 * wm + mi;
            if (mt < 7) {
                bf16x8 a[5];
                #pragma unroll
                for (int kt = 0; kt < 5; ++kt)
                    a[kt] = fragLds(sA1p + ((mt * 5 + kt) * 64 + ld) * 8);
                const bool ok = (mt < 6) || (Q == 0);   // D rows m = 16mt+4Q+r < 100
                #pragma unroll
                for (int t = 0; t < 3; ++t) {
                    const int nt = wn + 4 * t;          // 12 f-tiles over 4 wn
                    fx4 acc = (fx4){bias2[t], bias2[t], bias2[t], bias2[t]};
                    #pragma unroll
                    for (int kt = 0; kt < 5; ++kt) {
                        bf16x8 bw = fragGbl(W2p + (size_t)((kt * 12 + nt) * 64 + ld) * 8);
                        acc = MFMA(a[kt], bw, acc);
                    }
                    if (ok)
                        aggp[t] += lrelu(acc[0]) + lrelu(acc[1]) + lrelu(acc[2]) + lrelu(acc[3]);
                }
            }
        }
        // rows live across Q groups: 2-step shuffle reduce
        #pragma unroll
        for (int t = 0; t < 3; ++t) {
            aggp[t] += __shfl_xor(aggp[t], 16, 64);
            aggp[t] += __shfl_xor(aggp[t], 32, 64);
        }
        if (ld < 16) {
            #pragma unroll
            for (int t = 0; t < 3; ++t)
                sAggP[wm * F2 + 16 * (wn + 4 * t) + ld] = aggp[t];
        }
    }
    __syncthreads();

    if (tid < F2)
        agg[(size_t)row * F2 + tid] = f2bfu(sAggP[tid] + sAggP[F2 + tid]);
}

// ============================ node ============================
// 800 blocks x 8 rows (16-row MFMA tile, top half valid), 512 threads
__global__ __launch_bounds__(512, 4) void node_kernel(
    const u16* __restrict__ agg, const float* __restrict__ x,
    const u16* __restrict__ n0p, const u16* __restrict__ n1p,
    const u16* __restrict__ n2p,
    const float* __restrict__ fnb0, const float* __restrict__ fnb1,
    const float* __restrict__ fnb2,
    float* __restrict__ out)
{
    const int blk = blockIdx.x;
    const int tid = threadIdx.x, ld = tid & 63, wv = tid >> 6;
    const int c = ld & 15, Q = ld >> 4;

    __shared__ __align__(16) u16 sH0p[7 * 512];   //  7168 B
    __shared__ __align__(16) u16 sH1p[8 * 512];   //  8192 B
    __shared__ __align__(16) u16 sH2p[8 * 512];   //  8192 B

    // ---- stage H0 = [agg | x] in A-pack layout (rows 8..15 = clamped dup) ----
    if (tid < 448) {
        int kt = tid >> 6, lane = tid & 63;
        int m = lane & 15;
        int kb = 32 * kt + 8 * (lane >> 4);
        int g = NODE_ROWS * blk + ((m < NODE_ROWS) ? m : (NODE_ROWS - 1));
        uint4 w;
        if (kb < F2) {
            w = *(const uint4*)(agg + (size_t)g * F2 + kb);
        } else {
            const float* xp = x + (size_t)g * D_ + (kb - F2);
            float4 a = *(const float4*)xp;
            float4 bb = *(const float4*)(xp + 4);
            w.x = pk2(a.x, a.y);  w.y = pk2(a.z, a.w);
            w.z = pk2(bb.x, bb.y); w.w = pk2(bb.z, bb.w);
        }
        *(uint4*)&sH0p[tid * 8] = w;
    }
    __syncthreads();

    // ---- node layer 0: K=224, N=256 ; wave handles nt = wv, wv+8 ----
    {
        fx4 acc[2];
        #pragma unroll
        for (int t = 0; t < 2; ++t) acc[t] = (fx4){0.f, 0.f, 0.f, 0.f};
        for (int kt = 0; kt < 7; ++kt) {
            bf16x8 a = fragLds(sH0p + (kt * 64 + ld) * 8);
            #pragma unroll
            for (int t = 0; t < 2; ++t) {
                bf16x8 bw = fragGbl(n0p + (size_t)((kt * 16 + wv + 8 * t) * 64 + ld) * 8);
                acc[t] = MFMA(a, bw, acc[t]);
            }
        }
        #pragma unroll
        for (int t = 0; t < 2; ++t) {
            int f = 16 * (wv + 8 * t) + c;
            float bias = fnb0[f];
            int kt2 = f >> 5, o8 = (f >> 3) & 3, j2 = f & 7;
            #pragma unroll
            for (int r = 0; r < 4; ++r) {
                float val = lrelu(acc[t][r] + bias);
                sH1p[((kt2) * 64 + (4 * Q + r) + 16 * o8) * 8 + j2] = f2bfu(val);
            }
        }
    }
    __syncthreads();

    // ---- node layer 1: K=256, N=256 ----
    {
        fx4 acc[2];
        #pragma unroll
        for (int t = 0; t < 2; ++t) acc[t] = (fx4){0.f, 0.f, 0.f, 0.f};
        for (int kt = 0; kt < 8; ++kt) {
            bf16x8 a = fragLds(sH1p + (kt * 64 + ld) * 8);
            #pragma unroll
            for (int t = 0; t < 2; ++t) {
                bf16x8 bw = fragGbl(n1p + (size_t)((kt * 16 + wv + 8 * t) * 64 + ld) * 8);
                acc[t] = MFMA(a, bw, acc[t]);
            }
        }
        #pragma unroll
        for (int t = 0; t < 2; ++t) {
            int f = 16 * (wv + 8 * t) + c;
            float bias = fnb1[f];
            int kt2 = f >> 5, o8 = (f >> 3) & 3, j2 = f & 7;
            #pragma unroll
            for (int r = 0; r < 4; ++r) {
                float val = lrelu(acc[t][r] + bias);
                sH2p[((kt2) * 64 + (4 * Q + r) + 16 * o8) * 8 + j2] = f2bfu(val);
            }
        }
    }
    __syncthreads();

    // ---- node layer 2: K=256, N=32, linear -> out (rows 0..7 only) ----
    if (wv < 2) {
        int nt = wv;
        fx4 acc = (fx4){0.f, 0.f, 0.f, 0.f};
        for (int kt = 0; kt < 8; ++kt) {
            bf16x8 a = fragLds(sH2p + (kt * 64 + ld) * 8);
            bf16x8 bw = fragGbl(n2p + (size_t)((kt * 2 + nt) * 64 + ld) * 8);
            acc = MFMA(a, bw, acc);
        }
        if (Q < 2) {                       // rows 4Q+r < 8 valid
            int f = 16 * nt + c;
            float bias = fnb2[f];
            #pragma unroll
            for (int r = 0; r < 4; ++r) {
                int g = NODE_ROWS * blk + 4 * Q + r;
                out[(size_t)g * FOUT + f] = acc[r] + bias;
            }
        }
    }
}

extern "C" void kernel_launch(void* const* d_in, const int* in_sizes, int n_in,
                              void* d_out, int out_size, void* d_ws, size_t ws_size,
                              hipStream_t stream) {
    const float* x    = (const float*)d_in[0];
    const float* few0 = (const float*)d_in[1];
    const float* feb0 = (const float*)d_in[2];
    const float* few1 = (const float*)d_in[3];
    const float* feb1 = (const float*)d_in[4];
    const float* few2 = (const float*)d_in[5];
    const float* feb2 = (const float*)d_in[6];
    const float* fnw0 = (const float*)d_in[7];
    const float* fnb0 = (const float*)d_in[8];
    const float* fnw1 = (const float*)d_in[9];
    const float* fnb1 = (const float*)d_in[10];
    const float* fnw2 = (const float*)d_in[11];
    const float* fnb2 = (const float*)d_in[12];

    char* w = (char*)d_ws;
    float* P    = (float*)(w + OFF_P);
    float* V    = (float*)(w + OFF_V);
    u16*   agg  = (u16*)(w + OFF_AGG);
    u16*   pack = (u16*)(w + OFF_PACK);

    prep_kernel<<<PV_BLOCKS + PACK_BLOCKS, 512, 0, stream>>>(
        x, few0, feb0, few1, few2, fnw0, fnw1, fnw2, P, V, pack);

    edge_kernel<<<dim3(N_, B_), 512, 0, stream>>>(
        P, V, pack + PK_W1, pack + PK_W2, feb1, feb2, agg);

    node_kernel<<<NODE_BLOCKS, 512, 0, stream>>>(
        agg, x, pack + PK_N0, pack + PK_N1, pack + PK_N2,
        fnb0, fnb1, fnb2, (float*)d_out);
}